// Round 1
// baseline (676.813 us; speedup 1.0000x reference)
//
#include <hip/hip_runtime.h>
#include <math.h>

#define B_ 2
#define N_ 512
#define H_ 128
#define NT_ 3
#define SD_ 4
#define FD_ 5

// ---------------------------------------------------------------------------
// h0 = relu(feats @ W_in + b_in)
__global__ __launch_bounds__(128) void k_input(const float* __restrict__ feats,
                                               const float* __restrict__ W_in,
                                               const float* __restrict__ b_in,
                                               float* __restrict__ hout) {
    int node = blockIdx.x, tid = threadIdx.x;
    const float* f = feats + (size_t)node * FD_;
    float acc = b_in[tid];
#pragma unroll
    for (int k = 0; k < FD_; ++k) acc += f[k] * W_in[k * H_ + tid];
    hout[(size_t)node * H_ + tid] = fmaxf(acc, 0.f);
}

// ---------------------------------------------------------------------------
// msg = adj @ h ; h = relu([h,msg] @ W_mp[l] + b_mp[l])   (one block per node)
__global__ __launch_bounds__(128) void k_mp(const float* __restrict__ hin,
                                            float* __restrict__ hout,
                                            const float* __restrict__ adj,
                                            const float* __restrict__ Wl,
                                            const float* __restrict__ bl) {
    __shared__ float adjrow[N_];
    __shared__ float hi[H_];
    __shared__ float msg[H_];
    int node = blockIdx.x;      // b*N + i
    int b = node >> 9;
    int tid = threadIdx.x;
    const float* arow = adj + (size_t)node * N_;
    float4 av = ((const float4*)arow)[tid];          // 128 thr * 4 = 512
    *(float4*)&adjrow[tid * 4] = av;
    hi[tid] = hin[(size_t)node * H_ + tid];
    __syncthreads();

    float m = 0.f;
    const float* hb = hin + ((size_t)b * N_) * H_;
    for (int j = 0; j < N_; ++j) {
        float a = adjrow[j];                          // uniform across block
        if (a != 0.f) m += a * hb[(size_t)j * H_ + tid];
    }
    msg[tid] = m;
    __syncthreads();

    float acc = bl[tid];
#pragma unroll 4
    for (int k = 0; k < H_; ++k) {
        acc += hi[k]  * Wl[(size_t)k * H_ + tid];
        acc += msg[k] * Wl[(size_t)(k + H_) * H_ + tid];
    }
    hout[(size_t)node * H_ + tid] = fmaxf(acc, 0.f);
}

// ---------------------------------------------------------------------------
// heads (type/state) + per-node pair-MLP precomputes A_i (incl be1) and B_j
__global__ __launch_bounds__(128) void k_heads(
    const float* __restrict__ h, const float* __restrict__ feats,
    const float* __restrict__ snm,
    const float* __restrict__ Wt1, const float* __restrict__ bt1,
    const float* __restrict__ Wt2, const float* __restrict__ bt2,
    const float* __restrict__ Ws1, const float* __restrict__ bs1,
    const float* __restrict__ Ws2, const float* __restrict__ bs2,
    const float* __restrict__ We1, const float* __restrict__ be1,
    float* __restrict__ Acoef, float* __restrict__ Bcoef,
    float* __restrict__ type_out, float* __restrict__ state_out) {
    __shared__ float hi[H_], hT[H_], hS[H_];
    int node = blockIdx.x, tid = threadIdx.x;
    hi[tid] = h[(size_t)node * H_ + tid];
    __syncthreads();
    float at = bt1[tid], as = bs1[tid], aa = be1[tid], ab = 0.f;
#pragma unroll 4
    for (int k = 0; k < H_; ++k) {
        float hv = hi[k];
        at += hv * Wt1[k * H_ + tid];
        as += hv * Ws1[k * H_ + tid];
        aa += hv * We1[k * H_ + tid];            // W_a rows [0,128)
        ab += hv * We1[(k + H_) * H_ + tid];     // W_b rows [128,256)
    }
    hT[tid] = fmaxf(at, 0.f);
    hS[tid] = fmaxf(as, 0.f);
    Acoef[(size_t)node * H_ + tid] = aa;
    Bcoef[(size_t)node * H_ + tid] = ab;
    __syncthreads();
    float sm = snm[node];
    if (tid < NT_) {
        float tl = bt2[tid];
        for (int c = 0; c < H_; ++c) tl += hT[c] * Wt2[c * NT_ + tid];
        int ct = (int)feats[(size_t)node * FD_];
        ct = ct < 0 ? 0 : (ct > NT_ - 1 ? NT_ - 1 : ct);
        float cv = (tid == ct) ? 10.f : -10.f;
        type_out[(size_t)node * NT_ + tid] = (sm != 0.f) ? tl : cv;
    }
    if (tid >= 64 && tid < 64 + SD_) {
        int s = tid - 64;
        float sl = bs2[s];
        for (int c = 0; c < H_; ++c) sl += hS[c] * Ws2[c * SD_ + s];
        state_out[(size_t)node * SD_ + s] =
            sm * sl + (1.f - sm) * feats[(size_t)node * FD_ + 1 + s];
    }
}

// ---------------------------------------------------------------------------
// raw edl(i,j) for a 64-j tile of one (b,i). pre = A_i + B_j + T@Wc + U@Wd,
// edl = relu(pre) @ We2 + be2.  Block: 256 thr, thread tile 4j x 8c.
__global__ __launch_bounds__(256) void k_pair(const float* __restrict__ h,
                                              const float* __restrict__ Acoef,
                                              const float* __restrict__ Bcoef,
                                              const float* __restrict__ We1,
                                              const float* __restrict__ We2,
                                              const float* __restrict__ be2,
                                              float* __restrict__ edl_out) {
    __shared__ float hj[64][132];   // pad 132: <=2-way bank alias (free)
    __shared__ float hi[H_];
    __shared__ float aco[H_];
    __shared__ float edlacc[64][3];

    int bid = blockIdx.x;
    int jb = bid & 7;
    int i = (bid >> 3) & (N_ - 1);
    int b = bid >> 12;
    int tid = threadIdx.x;

    const float* hbase = h + ((size_t)b * N_) * H_;
    if (tid < H_) {
        hi[tid] = hbase[(size_t)i * H_ + tid];
        aco[tid] = Acoef[((size_t)b * N_ + i) * H_ + tid];
    }
    {
        const float4* src = (const float4*)(hbase + (size_t)(jb * 64) * H_);
        for (int idx = tid; idx < 64 * 32; idx += 256) {
            int j = idx >> 5, q = idx & 31;
            float4 v = src[j * 32 + q];
            *(float4*)&hj[j][q * 4] = v;
        }
    }
    __syncthreads();

    int c0 = (tid & 15) * 8;
    int j0 = (tid >> 4) * 4;

    float acc[4][8];
#pragma unroll
    for (int m = 0; m < 4; ++m)
#pragma unroll
        for (int q = 0; q < 8; ++q) acc[m][q] = 0.f;

    const float* wcp = We1 + (size_t)(2 * H_) * H_ + c0;   // |hi-hj| block
    const float* wdp = We1 + (size_t)(3 * H_) * H_ + c0;   // hi*hj block
#pragma unroll 4
    for (int k = 0; k < H_; ++k) {
        float hik = hi[k];
        float4 wc0 = *(const float4*)(wcp + (size_t)k * H_);
        float4 wc1 = *(const float4*)(wcp + (size_t)k * H_ + 4);
        float4 wd0 = *(const float4*)(wdp + (size_t)k * H_);
        float4 wd1 = *(const float4*)(wdp + (size_t)k * H_ + 4);
#pragma unroll
        for (int m = 0; m < 4; ++m) {
            float hv = hj[j0 + m][k];
            float t = fabsf(hik - hv);
            float u = hik * hv;
            acc[m][0] += t * wc0.x + 0.f; acc[m][0] += u * wd0.x;
            acc[m][1] += t * wc0.y;       acc[m][1] += u * wd0.y;
            acc[m][2] += t * wc0.z;       acc[m][2] += u * wd0.z;
            acc[m][3] += t * wc0.w;       acc[m][3] += u * wd0.w;
            acc[m][4] += t * wc1.x;       acc[m][4] += u * wd1.x;
            acc[m][5] += t * wc1.y;       acc[m][5] += u * wd1.y;
            acc[m][6] += t * wc1.z;       acc[m][6] += u * wd1.z;
            acc[m][7] += t * wc1.w;       acc[m][7] += u * wd1.w;
        }
    }

    // epilogue: + A_i + B_j, relu, @ We2 ; reduce across the 16 lanes / j-group
    const float* Bco = Bcoef + ((size_t)b * N_ + jb * 64) * H_;
#pragma unroll
    for (int m = 0; m < 4; ++m) {
        const float* br = Bco + (size_t)(j0 + m) * H_ + c0;
        float4 b0 = *(const float4*)br;
        float4 b1 = *(const float4*)(br + 4);
        float bj[8] = {b0.x, b0.y, b0.z, b0.w, b1.x, b1.y, b1.z, b1.w};
        float p0 = 0.f, p1 = 0.f, p2 = 0.f;
#pragma unroll
        for (int q = 0; q < 8; ++q) {
            int c = c0 + q;
            float pre = acc[m][q] + aco[c] + bj[q];
            float hd = pre > 0.f ? pre : 0.f;
            p0 += hd * We2[c * 3 + 0];
            p1 += hd * We2[c * 3 + 1];
            p2 += hd * We2[c * 3 + 2];
        }
        p0 += __shfl_xor(p0, 1, 16); p0 += __shfl_xor(p0, 2, 16);
        p0 += __shfl_xor(p0, 4, 16); p0 += __shfl_xor(p0, 8, 16);
        p1 += __shfl_xor(p1, 1, 16); p1 += __shfl_xor(p1, 2, 16);
        p1 += __shfl_xor(p1, 4, 16); p1 += __shfl_xor(p1, 8, 16);
        p2 += __shfl_xor(p2, 1, 16); p2 += __shfl_xor(p2, 2, 16);
        p2 += __shfl_xor(p2, 4, 16); p2 += __shfl_xor(p2, 8, 16);
        if ((tid & 15) == 0) {
            edlacc[j0 + m][0] = p0;
            edlacc[j0 + m][1] = p1;
            edlacc[j0 + m][2] = p2;
        }
    }
    __syncthreads();
    if (tid < 64) {
        int j = jb * 64 + tid;
        size_t base = (((size_t)b * N_ + i) * N_ + j) * 3;
        edl_out[base + 0] = edlacc[tid][0] + be2[0];
        edl_out[base + 1] = edlacc[tid][1] + be2[1];
        edl_out[base + 2] = edlacc[tid][2] + be2[2];
    }
}

// ---------------------------------------------------------------------------
// in-place symmetrize + mask/copy select + edge-logit decode
__global__ __launch_bounds__(256) void k_sym(float* __restrict__ edl,
                                             float* __restrict__ el,
                                             const float* __restrict__ sem,
                                             const float* __restrict__ adj) {
    size_t idx = (size_t)blockIdx.x * 256 + threadIdx.x;   // < B*N*N
    int j = idx & (N_ - 1);
    int i = (idx >> 9) & (N_ - 1);
    int b = (int)(idx >> 18);
    if (i > j) return;
    size_t bnn = (size_t)b * N_ * N_;
    if (i == j) {
        size_t p = bnn + (size_t)i * N_ + i;
        edl[p * 3 + 0] = 0.f; edl[p * 3 + 1] = 0.f; edl[p * 3 + 2] = 0.f;
        el[p] = -1e9f;
        return;
    }
    size_t pij = bnn + (size_t)i * N_ + j;
    size_t pji = bnn + (size_t)j * N_ + i;
    float s0 = 0.5f * (edl[pij * 3 + 0] + edl[pji * 3 + 0]);
    float s1 = 0.5f * (edl[pij * 3 + 1] + edl[pji * 3 + 1]);
    float s2 = 0.5f * (edl[pij * 3 + 2] + edl[pji * 3 + 2]);
    float a = adj[pij];   // symmetric by construction
    float cur = (a > 0.5f) ? 1.f : 0.f;
#pragma unroll
    for (int d = 0; d < 2; ++d) {
        size_t p = d ? pji : pij;
        float m = sem[p];
        float e0 = (m != 0.f) ? s0 : 10.f;
        float e1 = (m != 0.f) ? s1 : -10.f;
        float e2 = (m != 0.f) ? s2 : -10.f;
        edl[p * 3 + 0] = e0; edl[p * 3 + 1] = e1; edl[p * 3 + 2] = e2;
        float mx = fmaxf(e0, fmaxf(e1, e2));
        float x0 = expf(e0 - mx), x1 = expf(e1 - mx), x2 = expf(e2 - mx);
        float inv = 1.f / (x0 + x1 + x2);
        float pk = x0 * inv, pa = x1 * inv;
        float pn = pa + pk * cur;
        pn = fminf(fmaxf(pn, 1e-6f), 1.f - 1e-6f);
        el[p] = logf(pn) - log1pf(-pn);
    }
}

// ---------------------------------------------------------------------------
extern "C" void kernel_launch(void* const* d_in, const int* in_sizes, int n_in,
                              void* d_out, int out_size, void* d_ws,
                              size_t ws_size, hipStream_t stream) {
    const float* feats = (const float*)d_in[0];
    const float* adj   = (const float*)d_in[1];
    const float* snm   = (const float*)d_in[2];
    const float* sem   = (const float*)d_in[3];
    const float* W_in  = (const float*)d_in[4];
    const float* b_in  = (const float*)d_in[5];
    const float* W_mp  = (const float*)d_in[6];
    const float* b_mp  = (const float*)d_in[7];
    const float* Wt1 = (const float*)d_in[8],  *bt1 = (const float*)d_in[9];
    const float* Wt2 = (const float*)d_in[10], *bt2 = (const float*)d_in[11];
    const float* Ws1 = (const float*)d_in[12], *bs1 = (const float*)d_in[13];
    const float* Ws2 = (const float*)d_in[14], *bs2 = (const float*)d_in[15];
    const float* We1 = (const float*)d_in[16], *be1 = (const float*)d_in[17];
    const float* We2 = (const float*)d_in[18], *be2 = (const float*)d_in[19];

    float* out = (float*)d_out;
    float* type_out  = out;                       // B*N*NT  = 3072
    float* state_out = out + 3072;                // B*N*SD  = 4096
    float* edl_out   = out + 7168;                // B*N*N*3 = 1572864
    float* el_out    = out + 7168 + 1572864;      // B*N*N   = 524288

    float* ws = (float*)d_ws;
    float* hA = ws;                 // 131072
    float* hB = ws + 131072;        // 131072
    float* Ac = ws + 262144;        // 131072
    float* Bc = ws + 393216;        // 131072

    k_input<<<B_ * N_, H_, 0, stream>>>(feats, W_in, b_in, hA);
    k_mp<<<B_ * N_, H_, 0, stream>>>(hA, hB, adj, W_mp + 0 * 2 * H_ * H_, b_mp + 0 * H_);
    k_mp<<<B_ * N_, H_, 0, stream>>>(hB, hA, adj, W_mp + 1 * 2 * H_ * H_, b_mp + 1 * H_);
    k_mp<<<B_ * N_, H_, 0, stream>>>(hA, hB, adj, W_mp + 2 * 2 * H_ * H_, b_mp + 2 * H_);
    k_heads<<<B_ * N_, H_, 0, stream>>>(hB, feats, snm, Wt1, bt1, Wt2, bt2,
                                        Ws1, bs1, Ws2, bs2, We1, be1,
                                        Ac, Bc, type_out, state_out);
    k_pair<<<B_ * N_ * (N_ / 64), 256, 0, stream>>>(hB, Ac, Bc, We1, We2, be2, edl_out);
    k_sym<<<(B_ * N_ * N_) / 256, 256, 0, stream>>>(edl_out, el_out, sem, adj);
}

// Round 2
// 190.019 us; speedup vs baseline: 3.5618x; 3.5618x over previous
//
#include <hip/hip_runtime.h>
#include <math.h>

#define B_ 2
#define N_ 512
#define H_ 128
#define NT_ 3
#define SD_ 4
#define FD_ 5

typedef float f32x4 __attribute__((ext_vector_type(4)));
typedef unsigned int u32x4 __attribute__((ext_vector_type(4)));

// D,A,B,C — inline asm keeps us independent of builtin vector-type signatures.
// s_nop 1 covers VALU-write -> MFMA-read hazard on freshly built A frags.
#define MFMA16(acc, a, b) \
    asm("s_nop 1\n\tv_mfma_f32_16x16x32_bf16 %0, %1, %2, %0" \
        : "+v"(acc) : "v"(a), "v"(b))

#define CVTPK(d, a, b) \
    asm("v_cvt_pk_bf16_f32 %0, %1, %2" : "=v"(d) : "v"(a), "v"(b))

static __device__ inline unsigned rne1(float f) {
    unsigned u = __float_as_uint(f);
    u += 0x7fffu + ((u >> 16) & 1u);
    return u >> 16;
}

// full 16-lane (DPP row) sum via butterfly: xor1, xor2, half_mirror, mirror
static __device__ inline float red16(float v) {
    int x = __float_as_int(v);
    v += __int_as_float(__builtin_amdgcn_update_dpp(0, x, 0xB1, 0xF, 0xF, false));
    x = __float_as_int(v);
    v += __int_as_float(__builtin_amdgcn_update_dpp(0, x, 0x4E, 0xF, 0xF, false));
    x = __float_as_int(v);
    v += __int_as_float(__builtin_amdgcn_update_dpp(0, x, 0x141, 0xF, 0xF, false));
    x = __float_as_int(v);
    v += __int_as_float(__builtin_amdgcn_update_dpp(0, x, 0x140, 0xF, 0xF, false));
    return v;
}

// ---------------------------------------------------------------------------
__global__ __launch_bounds__(128) void k_input(const float* __restrict__ feats,
                                               const float* __restrict__ W_in,
                                               const float* __restrict__ b_in,
                                               float* __restrict__ hout) {
    int node = blockIdx.x, tid = threadIdx.x;
    const float* f = feats + (size_t)node * FD_;
    float acc = b_in[tid];
#pragma unroll
    for (int k = 0; k < FD_; ++k) acc += f[k] * W_in[k * H_ + tid];
    hout[(size_t)node * H_ + tid] = fmaxf(acc, 0.f);
}

// ---------------------------------------------------------------------------
// msg = adj @ h via deterministic ballot-compaction of the sparse row
__global__ __launch_bounds__(128) void k_mp(const float* __restrict__ hin,
                                            float* __restrict__ hout,
                                            const float* __restrict__ adj,
                                            const float* __restrict__ Wl,
                                            const float* __restrict__ bl) {
    __shared__ float hi[H_];
    __shared__ float msg[H_];
    __shared__ unsigned short idxs[N_];
    __shared__ float avals[N_];
    __shared__ int cnt2[2];
    int node = blockIdx.x;      // b*N + i
    int b = node >> 9;
    int tid = threadIdx.x;
    int w = tid >> 6, lane = tid & 63;
    hi[tid] = hin[(size_t)node * H_ + tid];
    const float* arow = adj + (size_t)node * N_;
    float4 av = ((const float4*)arow)[tid];          // j = tid*4..tid*4+3
    int segbase = w * 256;
    int cum = 0;
#pragma unroll
    for (int q = 0; q < 4; ++q) {
        float a = (&av.x)[q];
        bool pred = (a != 0.f);
        unsigned long long mask = __ballot(pred);
        if (pred) {
            int pos = segbase + cum +
                      (int)__popcll(mask & ((1ull << lane) - 1ull));
            idxs[pos] = (unsigned short)(tid * 4 + q);
            avals[pos] = a;
        }
        cum += (int)__popcll(mask);
    }
    if (lane == 0) cnt2[w] = cum;
    __syncthreads();

    float m = 0.f;
    const float* hb = hin + ((size_t)b * N_) * H_;
    int n0 = cnt2[0], n1 = cnt2[1];
    for (int t = 0; t < n0; ++t)
        m += avals[t] * hb[(size_t)idxs[t] * H_ + tid];
    for (int t = 0; t < n1; ++t)
        m += avals[256 + t] * hb[(size_t)idxs[256 + t] * H_ + tid];
    msg[tid] = m;
    __syncthreads();

    float acc = bl[tid];
#pragma unroll 4
    for (int k = 0; k < H_; ++k) {
        acc += hi[k]  * Wl[(size_t)k * H_ + tid];
        acc += msg[k] * Wl[(size_t)(k + H_) * H_ + tid];
    }
    hout[(size_t)node * H_ + tid] = fmaxf(acc, 0.f);
}

// ---------------------------------------------------------------------------
// heads + per-node pair precomputes A_i (incl be1), B_j, and bf16 copy of h
__global__ __launch_bounds__(128) void k_heads(
    const float* __restrict__ h, const float* __restrict__ feats,
    const float* __restrict__ snm,
    const float* __restrict__ Wt1, const float* __restrict__ bt1,
    const float* __restrict__ Wt2, const float* __restrict__ bt2,
    const float* __restrict__ Ws1, const float* __restrict__ bs1,
    const float* __restrict__ Ws2, const float* __restrict__ bs2,
    const float* __restrict__ We1, const float* __restrict__ be1,
    float* __restrict__ Acoef, float* __restrict__ Bcoef,
    unsigned short* __restrict__ hbf,
    float* __restrict__ type_out, float* __restrict__ state_out) {
    __shared__ float hi[H_], hT[H_], hS[H_];
    int node = blockIdx.x, tid = threadIdx.x;
    float hv0 = h[(size_t)node * H_ + tid];
    hi[tid] = hv0;
    hbf[(size_t)node * H_ + tid] = (unsigned short)rne1(hv0);
    __syncthreads();
    float at = bt1[tid], as = bs1[tid], aa = be1[tid], ab = 0.f;
#pragma unroll 4
    for (int k = 0; k < H_; ++k) {
        float hv = hi[k];
        at += hv * Wt1[k * H_ + tid];
        as += hv * Ws1[k * H_ + tid];
        aa += hv * We1[k * H_ + tid];            // W_a rows [0,128)
        ab += hv * We1[(k + H_) * H_ + tid];     // W_b rows [128,256)
    }
    hT[tid] = fmaxf(at, 0.f);
    hS[tid] = fmaxf(as, 0.f);
    Acoef[(size_t)node * H_ + tid] = aa;
    Bcoef[(size_t)node * H_ + tid] = ab;
    __syncthreads();
    float sm = snm[node];
    if (tid < NT_) {
        float tl = bt2[tid];
        for (int c = 0; c < H_; ++c) tl += hT[c] * Wt2[c * NT_ + tid];
        int ct = (int)feats[(size_t)node * FD_];
        ct = ct < 0 ? 0 : (ct > NT_ - 1 ? NT_ - 1 : ct);
        float cv = (tid == ct) ? 10.f : -10.f;
        type_out[(size_t)node * NT_ + tid] = (sm != 0.f) ? tl : cv;
    }
    if (tid >= 64 && tid < 64 + SD_) {
        int s = tid - 64;
        float sl = bs2[s];
        for (int c = 0; c < H_; ++c) sl += hS[c] * Ws2[c * SD_ + s];
        state_out[(size_t)node * SD_ + s] =
            sm * sl + (1.f - sm) * feats[(size_t)node * FD_ + 1 + s];
    }
}

// ---------------------------------------------------------------------------
// Pre-swizzle We1 rows [256:512) (Wc;Wd) into MFMA B-fragment layout:
// wfrag[kb][ctg][lane][8] bf16, element t of lane holds B[kb*32+8*(lane>>4)+t][ctg*16+(lane&15)]
__global__ __launch_bounds__(256) void k_wprep(const float* __restrict__ We1,
                                               unsigned short* __restrict__ wfrag) {
    int t = blockIdx.x * 256 + threadIdx.x;   // < 4096
    int lane = t & 63, ctg = (t >> 6) & 7, kb = t >> 9;
    int lr = lane & 15, g = lane >> 4;
    int c = ctg * 16 + lr;
    unsigned o[4];
#pragma unroll
    for (int p = 0; p < 4; ++p) {
        float a = We1[(size_t)(256 + kb * 32 + 8 * g + 2 * p) * H_ + c];
        float b = We1[(size_t)(256 + kb * 32 + 8 * g + 2 * p + 1) * H_ + c];
        o[p] = rne1(a) | (rne1(b) << 16);
    }
    u32x4 v = {o[0], o[1], o[2], o[3]};
    *(u32x4*)(wfrag + (size_t)t * 8) = v;
}

// ---------------------------------------------------------------------------
// MFMA pair kernel. Block: 256 thr = 4 waves (c-split, 32c each); block tile:
// one (b,i) x 64 j x 128 c, K=256 (kb 0-3: |hi-hj| @ Wc, kb 4-7: hi*hj @ Wd).
// Wave tile: 64j x 32c (JT=4 j-subtiles, CT=2), B-frags cached in VGPRs.
__global__ __launch_bounds__(256, 2) void k_pair_mfma(
    const float* __restrict__ h, const unsigned short* __restrict__ hbf,
    const float* __restrict__ Ac, const float* __restrict__ Bc,
    const unsigned short* __restrict__ wfrag,
    const float* __restrict__ We2, const float* __restrict__ be2,
    float* __restrict__ edl_out) {
    __shared__ float lds_o[4][64][3];

    int bid = blockIdx.x;
    int i  = bid & (N_ - 1);
    int jh = (bid >> 9) & 7;
    int b  = bid >> 12;
    int bN = b * N_;
    int j0 = jh * 64;

    int tid = threadIdx.x;
    int wc = tid >> 6;            // 0..3 -> c quarter
    int lane = tid & 63;
    int lr = lane & 15, g = lane >> 4;
    int c0 = wc * 32;

    // B fragments (CT=2 x 8 kb), each lane 16B, once per wave
    u32x4 Bf[2][8];
#pragma unroll
    for (int ct = 0; ct < 2; ++ct)
#pragma unroll
        for (int kb = 0; kb < 8; ++kb)
            Bf[ct][kb] = *(const u32x4*)(wfrag +
                (((size_t)kb * 8 + (wc * 2 + ct)) * 64 + lane) * 8);

    // hi windows: for m: hi[32m + 8g .. +8) as f32
    const float* hrow = h + (size_t)(bN + i) * H_;
    float him[4][8];
#pragma unroll
    for (int m = 0; m < 4; ++m) {
        float4 a = *(const float4*)(hrow + 32 * m + 8 * g);
        float4 bq = *(const float4*)(hrow + 32 * m + 8 * g + 4);
        him[m][0] = a.x;  him[m][1] = a.y;  him[m][2] = a.z;  him[m][3] = a.w;
        him[m][4] = bq.x; him[m][5] = bq.y; him[m][6] = bq.z; him[m][7] = bq.w;
    }

    float aco0 = Ac[(size_t)(bN + i) * H_ + c0 + lr];
    float aco1 = Ac[(size_t)(bN + i) * H_ + c0 + 16 + lr];
    float w2[2][3];
#pragma unroll
    for (int ct = 0; ct < 2; ++ct)
#pragma unroll
        for (int o = 0; o < 3; ++o)
            w2[ct][o] = We2[(size_t)(c0 + ct * 16 + lr) * 3 + o];

#pragma unroll
    for (int jt = 0; jt < 4; ++jt) {
        f32x4 acc0 = {0.f, 0.f, 0.f, 0.f};
        f32x4 acc1 = {0.f, 0.f, 0.f, 0.f};
        int jrow = j0 + jt * 16 + lr;          // A-frag source row
        const unsigned short* hjp = hbf + (size_t)(bN + jrow) * H_ + 8 * g;
        // issue all 4 m-chunk loads up front (latency overlap)
        u32x4 hjall[4];
#pragma unroll
        for (int m = 0; m < 4; ++m)
            hjall[m] = *(const u32x4*)(hjp + 32 * m);

#pragma unroll
        for (int m = 0; m < 4; ++m) {
            float hjf[8];
#pragma unroll
            for (int p = 0; p < 4; ++p) {
                unsigned d = hjall[m][p];
                hjf[2 * p]     = __uint_as_float(d << 16);
                hjf[2 * p + 1] = __uint_as_float(d & 0xffff0000u);
            }
            float tt[8], uu[8];
#pragma unroll
            for (int t = 0; t < 8; ++t) {
                tt[t] = fabsf(him[m][t] - hjf[t]);
                uu[t] = him[m][t] * hjf[t];
            }
            unsigned t0, t1, t2, t3, u0, u1, u2, u3;
            CVTPK(t0, tt[0], tt[1]); CVTPK(t1, tt[2], tt[3]);
            CVTPK(t2, tt[4], tt[5]); CVTPK(t3, tt[6], tt[7]);
            CVTPK(u0, uu[0], uu[1]); CVTPK(u1, uu[2], uu[3]);
            CVTPK(u2, uu[4], uu[5]); CVTPK(u3, uu[6], uu[7]);
            u32x4 tav = {t0, t1, t2, t3};
            u32x4 uav = {u0, u1, u2, u3};
            MFMA16(acc0, tav, Bf[0][m]);
            MFMA16(acc1, tav, Bf[1][m]);
            MFMA16(acc0, uav, Bf[0][4 + m]);
            MFMA16(acc1, uav, Bf[1][4 + m]);
        }
        // wait states before VALU reads MFMA results
        asm("s_nop 7\n\ts_nop 7\n\ts_nop 3" : "+v"(acc0), "+v"(acc1));

        // epilogue: +Ai +Bj, relu, @We2 partials, reduce over 16 c-lanes
        float bc0[4], bc1[4];
#pragma unroll
        for (int r = 0; r < 4; ++r) {
            int jg = j0 + jt * 16 + 4 * g + r;
            const float* bcr = Bc + (size_t)(bN + jg) * H_ + c0 + lr;
            bc0[r] = bcr[0];
            bc1[r] = bcr[16];
        }
#pragma unroll
        for (int r = 0; r < 4; ++r) {
            int jl = jt * 16 + 4 * g + r;
            float pre0 = acc0[r] + aco0 + bc0[r];
            float pre1 = acc1[r] + aco1 + bc1[r];
            float h0 = fmaxf(pre0, 0.f), h1 = fmaxf(pre1, 0.f);
            float s0 = h0 * w2[0][0] + h1 * w2[1][0];
            float s1 = h0 * w2[0][1] + h1 * w2[1][1];
            float s2 = h0 * w2[0][2] + h1 * w2[1][2];
            s0 = red16(s0); s1 = red16(s1); s2 = red16(s2);
            if (lr == 0) {
                lds_o[wc][jl][0] = s0;
                lds_o[wc][jl][1] = s1;
                lds_o[wc][jl][2] = s2;
            }
        }
    }
    __syncthreads();
    if (tid < 192) {
        int jl = tid / 3, o = tid - jl * 3;
        float v = lds_o[0][jl][o] + lds_o[1][jl][o] + lds_o[2][jl][o] +
                  lds_o[3][jl][o] + be2[o];
        edl_out[((size_t)(bN + i) * N_ + (j0 + jl)) * 3 + o] = v;
    }
}

// ---------------------------------------------------------------------------
// in-place symmetrize + mask/copy select + edge-logit decode
__global__ __launch_bounds__(256) void k_sym(float* __restrict__ edl,
                                             float* __restrict__ el,
                                             const float* __restrict__ sem,
                                             const float* __restrict__ adj) {
    size_t idx = (size_t)blockIdx.x * 256 + threadIdx.x;   // < B*N*N
    int j = idx & (N_ - 1);
    int i = (idx >> 9) & (N_ - 1);
    int b = (int)(idx >> 18);
    if (i > j) return;
    size_t bnn = (size_t)b * N_ * N_;
    if (i == j) {
        size_t p = bnn + (size_t)i * N_ + i;
        edl[p * 3 + 0] = 0.f; edl[p * 3 + 1] = 0.f; edl[p * 3 + 2] = 0.f;
        el[p] = -1e9f;
        return;
    }
    size_t pij = bnn + (size_t)i * N_ + j;
    size_t pji = bnn + (size_t)j * N_ + i;
    float s0 = 0.5f * (edl[pij * 3 + 0] + edl[pji * 3 + 0]);
    float s1 = 0.5f * (edl[pij * 3 + 1] + edl[pji * 3 + 1]);
    float s2 = 0.5f * (edl[pij * 3 + 2] + edl[pji * 3 + 2]);
    float a = adj[pij];   // symmetric by construction
    float cur = (a > 0.5f) ? 1.f : 0.f;
#pragma unroll
    for (int d = 0; d < 2; ++d) {
        size_t p = d ? pji : pij;
        float m = sem[p];
        float e0 = (m != 0.f) ? s0 : 10.f;
        float e1 = (m != 0.f) ? s1 : -10.f;
        float e2 = (m != 0.f) ? s2 : -10.f;
        edl[p * 3 + 0] = e0; edl[p * 3 + 1] = e1; edl[p * 3 + 2] = e2;
        float mx = fmaxf(e0, fmaxf(e1, e2));
        float x0 = expf(e0 - mx), x1 = expf(e1 - mx), x2 = expf(e2 - mx);
        float inv = 1.f / (x0 + x1 + x2);
        float pk = x0 * inv, pa = x1 * inv;
        float pn = pa + pk * cur;
        pn = fminf(fmaxf(pn, 1e-6f), 1.f - 1e-6f);
        el[p] = logf(pn) - log1pf(-pn);
    }
}

// ---------------------------------------------------------------------------
extern "C" void kernel_launch(void* const* d_in, const int* in_sizes, int n_in,
                              void* d_out, int out_size, void* d_ws,
                              size_t ws_size, hipStream_t stream) {
    const float* feats = (const float*)d_in[0];
    const float* adj   = (const float*)d_in[1];
    const float* snm   = (const float*)d_in[2];
    const float* sem   = (const float*)d_in[3];
    const float* W_in  = (const float*)d_in[4];
    const float* b_in  = (const float*)d_in[5];
    const float* W_mp  = (const float*)d_in[6];
    const float* b_mp  = (const float*)d_in[7];
    const float* Wt1 = (const float*)d_in[8],  *bt1 = (const float*)d_in[9];
    const float* Wt2 = (const float*)d_in[10], *bt2 = (const float*)d_in[11];
    const float* Ws1 = (const float*)d_in[12], *bs1 = (const float*)d_in[13];
    const float* Ws2 = (const float*)d_in[14], *bs2 = (const float*)d_in[15];
    const float* We1 = (const float*)d_in[16], *be1 = (const float*)d_in[17];
    const float* We2 = (const float*)d_in[18], *be2 = (const float*)d_in[19];

    float* out = (float*)d_out;
    float* type_out  = out;                       // B*N*NT  = 3072
    float* state_out = out + 3072;                // B*N*SD  = 4096
    float* edl_out   = out + 7168;                // B*N*N*3 = 1572864
    float* el_out    = out + 7168 + 1572864;      // B*N*N   = 524288

    float* ws = (float*)d_ws;
    float* hA = ws;                               // 131072 f  (later: Ac)
    float* hB = ws + 131072;                      // 131072 f  (final h)
    float* Bc = ws + 262144;                      // 131072 f
    unsigned short* hbf   = (unsigned short*)(ws + 393216);   // 131072 bf16
    unsigned short* wfrag = (unsigned short*)(ws + 458752);   // 32768 bf16
    float* Acf = hA;                              // reuse hA (dead after mp)

    k_input<<<B_ * N_, H_, 0, stream>>>(feats, W_in, b_in, hA);
    k_mp<<<B_ * N_, H_, 0, stream>>>(hA, hB, adj, W_mp + 0 * 2 * H_ * H_, b_mp + 0 * H_);
    k_mp<<<B_ * N_, H_, 0, stream>>>(hB, hA, adj, W_mp + 1 * 2 * H_ * H_, b_mp + 1 * H_);
    k_mp<<<B_ * N_, H_, 0, stream>>>(hA, hB, adj, W_mp + 2 * 2 * H_ * H_, b_mp + 2 * H_);
    k_wprep<<<16, 256, 0, stream>>>(We1, wfrag);
    k_heads<<<B_ * N_, H_, 0, stream>>>(hB, feats, snm, Wt1, bt1, Wt2, bt2,
                                        Ws1, bs1, Ws2, bs2, We1, be1,
                                        Acf, Bc, hbf, type_out, state_out);
    k_pair_mfma<<<B_ * N_ * 8, 256, 0, stream>>>(hB, hbf, Acf, Bc, wfrag,
                                                 We2, be2, edl_out);
    k_sym<<<(B_ * N_ * N_) / 256, 256, 0, stream>>>(edl_out, el_out, sem, adj);
}

// Round 3
// 127.573 us; speedup vs baseline: 5.3053x; 1.4895x over previous
//
#include <hip/hip_runtime.h>
#include <math.h>

#define B_ 2
#define N_ 512
#define H_ 128
#define NT_ 3
#define SD_ 4
#define FD_ 5

typedef float f32x4 __attribute__((ext_vector_type(4)));
typedef unsigned int u32x4 __attribute__((ext_vector_type(4)));

#define MFMA16(acc, a, b) \
    asm("s_nop 1\n\tv_mfma_f32_16x16x32_bf16 %0, %1, %2, %0" \
        : "+v"(acc) : "v"(a), "v"(b))

#define CVTPK(d, a, b) \
    asm("v_cvt_pk_bf16_f32 %0, %1, %2" : "=v"(d) : "v"(a), "v"(b))

// abs input modifiers: packs |a|,|b|
#define CVTPKA(d, a, b) \
    asm("v_cvt_pk_bf16_f32 %0, |%1|, |%2|" : "=v"(d) : "v"(a), "v"(b))

static __device__ inline unsigned rne1(float f) {
    unsigned u = __float_as_uint(f);
    u += 0x7fffu + ((u >> 16) & 1u);
    return u >> 16;
}

// ---------------------------------------------------------------------------
// h0 = relu(feats @ W_in + b_in); extra blocks: prep main-GEMM B-frags (wfrag)
// and pi-permuted We2 proj B-frags (wfrag2)
__global__ __launch_bounds__(128) void k_input(const float* __restrict__ feats,
                                               const float* __restrict__ W_in,
                                               const float* __restrict__ b_in,
                                               float* __restrict__ hout,
                                               const float* __restrict__ We1,
                                               const float* __restrict__ We2,
                                               unsigned short* __restrict__ wfrag,
                                               unsigned short* __restrict__ wfrag2) {
    int blk = blockIdx.x, tid = threadIdx.x;
    if (blk < B_ * N_) {
        const float* f = feats + (size_t)blk * FD_;
        float acc = b_in[tid];
#pragma unroll
        for (int k = 0; k < FD_; ++k) acc += f[k] * W_in[k * H_ + tid];
        hout[(size_t)blk * H_ + tid] = fmaxf(acc, 0.f);
        return;
    }
    if (blk < B_ * N_ + 32) {
        // main-GEMM B fragments: wfrag[kb][cg][lane][8]
        int t = (blk - B_ * N_) * 128 + tid;   // < 4096
        int lane = t & 63, cg = (t >> 6) & 7, kb = t >> 9;
        int lr = lane & 15, g = lane >> 4;
        int c = cg * 16 + lr;
        unsigned o[4];
#pragma unroll
        for (int p = 0; p < 4; ++p) {
            float a = We1[(size_t)(256 + kb * 32 + 8 * g + 2 * p) * H_ + c];
            float bq = We1[(size_t)(256 + kb * 32 + 8 * g + 2 * p + 1) * H_ + c];
            o[p] = rne1(a) | (rne1(bq) << 16);
        }
        u32x4 v = {o[0], o[1], o[2], o[3]};
        *(u32x4*)(wfrag + (size_t)t * 8) = v;
        return;
    }
    {
        // proj B fragments (We2, k-rows pi-permuted): wfrag2[kb][lane][8]
        int t = (blk - (B_ * N_ + 32)) * 128 + tid;
        if (t < 256) {
            int kb = t >> 6, lane = t & 63;
            int oc = lane & 15, g = lane >> 4;
            unsigned w[4];
#pragma unroll
            for (int p = 0; p < 4; ++p) {
                int k0 = kb * 32 + g * 8 + 2 * p;
                int k1 = k0 + 1;
                int c0 = ((k0 >> 6) << 6) | ((k0 & 3) << 4) | ((k0 & 63) >> 2);
                int c1 = ((k1 >> 6) << 6) | ((k1 & 3) << 4) | ((k1 & 63) >> 2);
                float v0 = (oc < 3) ? We2[c0 * 3 + oc] : 0.f;
                float v1 = (oc < 3) ? We2[c1 * 3 + oc] : 0.f;
                w[p] = rne1(v0) | (rne1(v1) << 16);
            }
            u32x4 v = {w[0], w[1], w[2], w[3]};
            *(u32x4*)(wfrag2 + (size_t)t * 8) = v;
        }
    }
}

// ---------------------------------------------------------------------------
// msg = adj @ h via deterministic ballot-compaction of the sparse row
__global__ __launch_bounds__(128) void k_mp(const float* __restrict__ hin,
                                            float* __restrict__ hout,
                                            const float* __restrict__ adj,
                                            const float* __restrict__ Wl,
                                            const float* __restrict__ bl) {
    __shared__ float hi[H_];
    __shared__ float msg[H_];
    __shared__ unsigned short idxs[N_];
    __shared__ float avals[N_];
    __shared__ int cnt2[2];
    int node = blockIdx.x;      // b*N + i
    int b = node >> 9;
    int tid = threadIdx.x;
    int w = tid >> 6, lane = tid & 63;
    hi[tid] = hin[(size_t)node * H_ + tid];
    const float* arow = adj + (size_t)node * N_;
    float4 av = ((const float4*)arow)[tid];
    int segbase = w * 256;
    int cum = 0;
#pragma unroll
    for (int q = 0; q < 4; ++q) {
        float a = (&av.x)[q];
        bool pred = (a != 0.f);
        unsigned long long mask = __ballot(pred);
        if (pred) {
            int pos = segbase + cum +
                      (int)__popcll(mask & ((1ull << lane) - 1ull));
            idxs[pos] = (unsigned short)(tid * 4 + q);
            avals[pos] = a;
        }
        cum += (int)__popcll(mask);
    }
    if (lane == 0) cnt2[w] = cum;
    __syncthreads();

    float m = 0.f;
    const float* hb = hin + ((size_t)b * N_) * H_;
    int n0 = cnt2[0], n1 = cnt2[1];
    for (int t = 0; t < n0; ++t)
        m += avals[t] * hb[(size_t)idxs[t] * H_ + tid];
    for (int t = 0; t < n1; ++t)
        m += avals[256 + t] * hb[(size_t)idxs[256 + t] * H_ + tid];
    msg[tid] = m;
    __syncthreads();

    float acc = bl[tid];
#pragma unroll 4
    for (int k = 0; k < H_; ++k) {
        acc += hi[k]  * Wl[(size_t)k * H_ + tid];
        acc += msg[k] * Wl[(size_t)(k + H_) * H_ + tid];
    }
    hout[(size_t)node * H_ + tid] = fmaxf(acc, 0.f);
}

// ---------------------------------------------------------------------------
// heads + pi-scattered per-node precomputes A_i (incl be1), B_j, bf16 h copy
__global__ __launch_bounds__(128) void k_heads(
    const float* __restrict__ h, const float* __restrict__ feats,
    const float* __restrict__ snm,
    const float* __restrict__ Wt1, const float* __restrict__ bt1,
    const float* __restrict__ Wt2, const float* __restrict__ bt2,
    const float* __restrict__ Ws1, const float* __restrict__ bs1,
    const float* __restrict__ Ws2, const float* __restrict__ bs2,
    const float* __restrict__ We1, const float* __restrict__ be1,
    float* __restrict__ Acoef, float* __restrict__ Bcoef,
    unsigned short* __restrict__ hbf,
    float* __restrict__ type_out, float* __restrict__ state_out) {
    __shared__ float hi[H_], hT[H_], hS[H_];
    int node = blockIdx.x, tid = threadIdx.x;
    float hv0 = h[(size_t)node * H_ + tid];
    hi[tid] = hv0;
    hbf[(size_t)node * H_ + tid] = (unsigned short)rne1(hv0);
    __syncthreads();
    float at = bt1[tid], as = bs1[tid], aa = be1[tid], ab = 0.f;
#pragma unroll 4
    for (int k = 0; k < H_; ++k) {
        float hv = hi[k];
        at += hv * Wt1[k * H_ + tid];
        as += hv * Ws1[k * H_ + tid];
        aa += hv * We1[k * H_ + tid];            // W_a rows [0,128)
        ab += hv * We1[(k + H_) * H_ + tid];     // W_b rows [128,256)
    }
    hT[tid] = fmaxf(at, 0.f);
    hS[tid] = fmaxf(as, 0.f);
    // pi-position: c = ch*64 + ct*16 + lr  ->  k' = ch*64 + lr*4 + ct
    int c = tid;
    int kp = ((c >> 6) << 6) | ((c & 15) << 2) | ((c >> 4) & 3);
    Acoef[(size_t)node * H_ + kp] = aa;
    Bcoef[(size_t)node * H_ + kp] = ab;
    __syncthreads();
    float sm = snm[node];
    if (tid < NT_) {
        float tl = bt2[tid];
        for (int cc = 0; cc < H_; ++cc) tl += hT[cc] * Wt2[cc * NT_ + tid];
        int ct = (int)feats[(size_t)node * FD_];
        ct = ct < 0 ? 0 : (ct > NT_ - 1 ? NT_ - 1 : ct);
        float cv = (tid == ct) ? 10.f : -10.f;
        type_out[(size_t)node * NT_ + tid] = (sm != 0.f) ? tl : cv;
    }
    if (tid >= 64 && tid < 64 + SD_) {
        int s = tid - 64;
        float sl = bs2[s];
        for (int cc = 0; cc < H_; ++cc) sl += hS[cc] * Ws2[cc * SD_ + s];
        state_out[(size_t)node * SD_ + s] =
            sm * sl + (1.f - sm) * feats[(size_t)node * FD_ + 1 + s];
    }
}

// ---------------------------------------------------------------------------
// Fused pair kernel: unordered (i, 128-j-tile) blocks. Main GEMM computes the
// symmetric T+U once; epilogue builds BOTH orientations' hidden (pi-packed
// bf16 into swizzled LDS), proj-MFMA vs pre-permuted We2 frags, then in-block
// symmetrize + mask + decode, writing edl/el for (i,j) and (j,i).
__global__ __launch_bounds__(256, 2) void k_pair2(
    const float* __restrict__ h, const unsigned short* __restrict__ hbf,
    const float* __restrict__ Acp, const float* __restrict__ Bcp,
    const unsigned short* __restrict__ wfrag,
    const unsigned short* __restrict__ wfrag2,
    const float* __restrict__ be2, const float* __restrict__ sem,
    const float* __restrict__ adj,
    float* __restrict__ edl_out, float* __restrict__ el_out) {

    __shared__ unsigned short tile[2][128][128];   // 64KB pi-packed bf16

    int bid = blockIdx.x;
    int b = 0, r = bid;
    if (r >= 1280) { b = 1; r -= 1280; }
    int jtile, i;
    if (r < 128)      { jtile = 0; i = r; }
    else if (r < 384) { jtile = 1; i = r - 128; }
    else if (r < 768) { jtile = 2; i = r - 384; }
    else              { jtile = 3; i = r - 768; }
    int JT0 = jtile << 7;
    bool diagblk = (jtile == (i >> 7));
    int bN = b << 9;

    int tid = threadIdx.x;
    int wave = tid >> 6, lane = tid & 63;
    int jh = wave >> 1, ch = wave & 1;
    int lr = lane & 15, g = lane >> 4;

    // main-GEMM B fragments: 4 ct (cg = ch*4+ct) x 8 kb  (128 VGPR)
    u32x4 Bf[4][8];
#pragma unroll
    for (int ct = 0; ct < 4; ++ct)
#pragma unroll
        for (int kb = 0; kb < 8; ++kb)
            Bf[ct][kb] = *(const u32x4*)(wfrag +
                (((size_t)kb * 8 + (ch * 4 + ct)) * 64 + lane) * 8);

    const float* hrow = h + (size_t)(bN + i) * H_;
    float him[4][8];
#pragma unroll
    for (int m = 0; m < 4; ++m) {
        float4 a = *(const float4*)(hrow + 32 * m + 8 * g);
        float4 bq = *(const float4*)(hrow + 32 * m + 8 * g + 4);
        him[m][0] = a.x;  him[m][1] = a.y;  him[m][2] = a.z;  him[m][3] = a.w;
        him[m][4] = bq.x; him[m][5] = bq.y; him[m][6] = bq.z; him[m][7] = bq.w;
    }

    f32x4 AcoI = *(const f32x4*)(Acp + (size_t)(bN + i) * H_ + ch * 64 + lr * 4);
    f32x4 BcoI = *(const f32x4*)(Bcp + (size_t)(bN + i) * H_ + ch * 64 + lr * 4);

    char* tb0 = (char*)&tile[0][0][0];
    char* tb1 = (char*)&tile[1][0][0];

#pragma unroll
    for (int jt = 0; jt < 4; ++jt) {
        int jloc0 = jh * 64 + jt * 16;
        const unsigned short* hjp =
            hbf + (size_t)(bN + JT0 + jloc0 + lr) * H_ + 8 * g;
        u32x4 hjall[4];
#pragma unroll
        for (int m = 0; m < 4; ++m)
            hjall[m] = *(const u32x4*)(hjp + 32 * m);

        f32x4 acc0 = {0.f, 0.f, 0.f, 0.f};
        f32x4 acc1 = {0.f, 0.f, 0.f, 0.f};
        f32x4 acc2 = {0.f, 0.f, 0.f, 0.f};
        f32x4 acc3 = {0.f, 0.f, 0.f, 0.f};

#pragma unroll
        for (int m = 0; m < 4; ++m) {
            float hjf[8];
#pragma unroll
            for (int p = 0; p < 4; ++p) {
                unsigned d = hjall[m][p];
                hjf[2 * p]     = __uint_as_float(d << 16);
                hjf[2 * p + 1] = __uint_as_float(d & 0xffff0000u);
            }
            float tt[8], uu[8];
#pragma unroll
            for (int t = 0; t < 8; ++t) {
                tt[t] = him[m][t] - hjf[t];      // abs folded into cvt
                uu[t] = him[m][t] * hjf[t];
            }
            unsigned t0, t1, t2, t3, u0, u1, u2, u3;
            CVTPKA(t0, tt[0], tt[1]); CVTPKA(t1, tt[2], tt[3]);
            CVTPKA(t2, tt[4], tt[5]); CVTPKA(t3, tt[6], tt[7]);
            CVTPK(u0, uu[0], uu[1]); CVTPK(u1, uu[2], uu[3]);
            CVTPK(u2, uu[4], uu[5]); CVTPK(u3, uu[6], uu[7]);
            u32x4 tav = {t0, t1, t2, t3};
            u32x4 uav = {u0, u1, u2, u3};
            MFMA16(acc0, tav, Bf[0][m]);
            MFMA16(acc1, tav, Bf[1][m]);
            MFMA16(acc2, tav, Bf[2][m]);
            MFMA16(acc3, tav, Bf[3][m]);
            MFMA16(acc0, uav, Bf[0][4 + m]);
            MFMA16(acc1, uav, Bf[1][4 + m]);
            MFMA16(acc2, uav, Bf[2][4 + m]);
            MFMA16(acc3, uav, Bf[3][4 + m]);
        }
        asm("s_nop 7\n\ts_nop 7\n\ts_nop 3"
            : "+v"(acc0), "+v"(acc1), "+v"(acc2), "+v"(acc3));

        // both-orientation hidden: pre1 = TU + A_i + B_j ; pre2 = TU + A_j + B_i
#pragma unroll
        for (int rr = 0; rr < 4; ++rr) {
            int jloc = jloc0 + 4 * g + rr;
            size_t jn = (size_t)(bN + JT0 + jloc) * H_ + ch * 64 + lr * 4;
            f32x4 BcJ = *(const f32x4*)(Bcp + jn);
            f32x4 AcJ = *(const f32x4*)(Acp + jn);
            float h10 = fmaxf(acc0[rr] + AcoI[0] + BcJ[0], 0.f);
            float h11 = fmaxf(acc1[rr] + AcoI[1] + BcJ[1], 0.f);
            float h12 = fmaxf(acc2[rr] + AcoI[2] + BcJ[2], 0.f);
            float h13 = fmaxf(acc3[rr] + AcoI[3] + BcJ[3], 0.f);
            float h20 = fmaxf(acc0[rr] + AcJ[0] + BcoI[0], 0.f);
            float h21 = fmaxf(acc1[rr] + AcJ[1] + BcoI[1], 0.f);
            float h22 = fmaxf(acc2[rr] + AcJ[2] + BcoI[2], 0.f);
            float h23 = fmaxf(acc3[rr] + AcJ[3] + BcoI[3], 0.f);
            unsigned w10, w11, w20, w21;
            CVTPK(w10, h10, h11); CVTPK(w11, h12, h13);
            CVTPK(w20, h20, h21); CVTPK(w21, h22, h23);
            int byte = jloc * 256 + ch * 128 + lr * 8;
            byte ^= (jloc & 7) << 4;
            uint2 v1; v1.x = w10; v1.y = w11;
            uint2 v2; v2.x = w20; v2.y = w21;
            *(uint2*)(tb0 + byte) = v1;
            *(uint2*)(tb1 + byte) = v2;
        }
    }

    // proj B-frags (pre-permuted We2)
    u32x4 Bf2[4];
#pragma unroll
    for (int kb = 0; kb < 4; ++kb)
        Bf2[kb] = *(const u32x4*)(wfrag2 + ((size_t)kb * 64 + lane) * 8);

    __syncthreads();

    // projection MFMAs: 16 subtiles (2 orient x 8), 4 per wave
    f32x4 pacc0 = {0.f,0.f,0.f,0.f}, pacc1 = {0.f,0.f,0.f,0.f};
    f32x4 pacc2 = {0.f,0.f,0.f,0.f}, pacc3 = {0.f,0.f,0.f,0.f};
#pragma unroll
    for (int p = 0; p < 4; ++p) {
        int f = wave + 4 * p;
        int orient = f >> 3, sub = f & 7;
        char* tb = orient ? tb1 : tb0;
        int jloc = sub * 16 + lr;
#pragma unroll
        for (int kb = 0; kb < 4; ++kb) {
            int byte = jloc * 256 + kb * 64 + g * 16;
            byte ^= (jloc & 7) << 4;
            u32x4 a = *(const u32x4*)(tb + byte);
            if (p == 0) { MFMA16(pacc0, a, Bf2[kb]); }
            else if (p == 1) { MFMA16(pacc1, a, Bf2[kb]); }
            else if (p == 2) { MFMA16(pacc2, a, Bf2[kb]); }
            else { MFMA16(pacc3, a, Bf2[kb]); }
        }
    }
    asm("s_nop 7\n\ts_nop 7\n\ts_nop 3"
        : "+v"(pacc0), "+v"(pacc1), "+v"(pacc2), "+v"(pacc3));
    __syncthreads();   // all tile reads done -> safe to alias as sbuf

    float* sbuf = (float*)&tile[0][0][0];  // [2][128][3]
    if (lr < 3) {
#pragma unroll
        for (int p = 0; p < 4; ++p) {
            int f = wave + 4 * p;
            int orient = f >> 3, sub = f & 7;
            f32x4 pa = (p == 0) ? pacc0 : (p == 1) ? pacc1 : (p == 2) ? pacc2 : pacc3;
#pragma unroll
            for (int rr = 0; rr < 4; ++rr) {
                int jloc = sub * 16 + 4 * g + rr;
                sbuf[((orient << 7) + jloc) * 3 + lr] = pa[rr];
            }
        }
    }
    __syncthreads();

    // decode: one thread per (jloc, direction)
    {
        int d = tid & 1, jloc = tid >> 1;
        int jg = JT0 + jloc;
        bool skip = diagblk && (jg < i);
        if (!skip) {
            float s0 = 0.5f * (sbuf[jloc * 3 + 0] + sbuf[(128 + jloc) * 3 + 0]) + be2[0];
            float s1 = 0.5f * (sbuf[jloc * 3 + 1] + sbuf[(128 + jloc) * 3 + 1]) + be2[1];
            float s2 = 0.5f * (sbuf[jloc * 3 + 2] + sbuf[(128 + jloc) * 3 + 2]) + be2[2];
            size_t p = d ? ((size_t)(bN + jg) * N_ + i)
                         : ((size_t)(bN + i) * N_ + jg);
            if (jg == i) {
                edl_out[p * 3 + 0] = 0.f;
                edl_out[p * 3 + 1] = 0.f;
                edl_out[p * 3 + 2] = 0.f;
                el_out[p] = -1e9f;
            } else {
                float msk = sem[p];
                float e0 = (msk != 0.f) ? s0 : 10.f;
                float e1 = (msk != 0.f) ? s1 : -10.f;
                float e2 = (msk != 0.f) ? s2 : -10.f;
                edl_out[p * 3 + 0] = e0;
                edl_out[p * 3 + 1] = e1;
                edl_out[p * 3 + 2] = e2;
                float a = adj[p];
                float cur = (a > 0.5f) ? 1.f : 0.f;
                float mx = fmaxf(e0, fmaxf(e1, e2));
                float x0 = expf(e0 - mx), x1 = expf(e1 - mx), x2 = expf(e2 - mx);
                float inv = 1.f / (x0 + x1 + x2);
                float pn = x1 * inv + x0 * inv * cur;
                pn = fminf(fmaxf(pn, 1e-6f), 1.f - 1e-6f);
                el_out[p] = logf(pn) - log1pf(-pn);
            }
        }
    }
}

// ---------------------------------------------------------------------------
extern "C" void kernel_launch(void* const* d_in, const int* in_sizes, int n_in,
                              void* d_out, int out_size, void* d_ws,
                              size_t ws_size, hipStream_t stream) {
    const float* feats = (const float*)d_in[0];
    const float* adj   = (const float*)d_in[1];
    const float* snm   = (const float*)d_in[2];
    const float* sem   = (const float*)d_in[3];
    const float* W_in  = (const float*)d_in[4];
    const float* b_in  = (const float*)d_in[5];
    const float* W_mp  = (const float*)d_in[6];
    const float* b_mp  = (const float*)d_in[7];
    const float* Wt1 = (const float*)d_in[8],  *bt1 = (const float*)d_in[9];
    const float* Wt2 = (const float*)d_in[10], *bt2 = (const float*)d_in[11];
    const float* Ws1 = (const float*)d_in[12], *bs1 = (const float*)d_in[13];
    const float* Ws2 = (const float*)d_in[14], *bs2 = (const float*)d_in[15];
    const float* We1 = (const float*)d_in[16], *be1 = (const float*)d_in[17];
    const float* We2 = (const float*)d_in[18], *be2 = (const float*)d_in[19];

    float* out = (float*)d_out;
    float* type_out  = out;                       // B*N*NT  = 3072
    float* state_out = out + 3072;                // B*N*SD  = 4096
    float* edl_out   = out + 7168;                // B*N*N*3 = 1572864
    float* el_out    = out + 7168 + 1572864;      // B*N*N   = 524288

    float* ws = (float*)d_ws;
    float* hA = ws;                               // 131072 f (h0 -> Acpi)
    float* hB = ws + 131072;                      // 131072 f (final h)
    float* Bcp = ws + 262144;                     // 131072 f
    unsigned short* hbf    = (unsigned short*)(ws + 393216);  // 131072 bf16
    unsigned short* wfrag  = (unsigned short*)(ws + 458752);  // 32768 bf16
    unsigned short* wfrag2 = (unsigned short*)(ws + 475136);  // 2048 bf16
    float* Acp = hA;                              // reuse (dead after mp3)

    k_input<<<B_ * N_ + 34, 128, 0, stream>>>(feats, W_in, b_in, hA,
                                              We1, We2, wfrag, wfrag2);
    k_mp<<<B_ * N_, H_, 0, stream>>>(hA, hB, adj, W_mp + 0 * 2 * H_ * H_, b_mp + 0 * H_);
    k_mp<<<B_ * N_, H_, 0, stream>>>(hB, hA, adj, W_mp + 1 * 2 * H_ * H_, b_mp + 1 * H_);
    k_mp<<<B_ * N_, H_, 0, stream>>>(hA, hB, adj, W_mp + 2 * 2 * H_ * H_, b_mp + 2 * H_);
    k_heads<<<B_ * N_, H_, 0, stream>>>(hB, feats, snm, Wt1, bt1, Wt2, bt2,
                                        Ws1, bs1, Ws2, bs2, We1, be1,
                                        Acp, Bcp, hbf, type_out, state_out);
    k_pair2<<<2560, 256, 0, stream>>>(hB, hbf, Acp, Bcp, wfrag, wfrag2,
                                      be2, sem, adj, edl_out, el_out);
}